// Round 2
// baseline (322.935 us; speedup 1.0000x reference)
//
#include <hip/hip_runtime.h>

#define BINS 10
#define TPB 256
#define VEC_ITERS 8    // float4 iterations per thread => 32 elements/thread

// Per-element fused math + LDS histogram accumulate.
// atomicAdd on __shared__ float emits no-return ds_add_f32: fire-and-forget,
// no lgkmcnt dependency chain (the round-1 kernel serialized on LDS RMW latency).
__device__ __forceinline__ void ghmc_accum(float z, int t,
                                           float* lsum, float* lcnt, int tid) {
    float tf = (float)t;
    float az = fabsf(z);
    float e  = __expf(-az);                  // exp(-|z|)
    float q  = 1.0f + e;
    float r  = __builtin_amdgcn_rcpf(q);     // ~1/(1+e)
    float s  = (z >= 0.0f) ? r : e * r;      // sigmoid(z)
    float g  = fabsf(s - tf);
    int bin  = (int)(g * 9.9999f);           // g>=0: trunc == floor
    bin = bin < (BINS - 1) ? bin : (BINS - 1);
    // ce = logaddexp(0,z) - z*t = max(z,0) + log(1+exp(-|z|)) - z*t
    float ce = fmaxf(z, 0.0f) - z * tf + __logf(q);
    atomicAdd(&lsum[bin * TPB + tid], ce);   // ds_add_f32 (no rtn)
    atomicAdd(&lcnt[bin * TPB + tid], 1.0f);
}

__global__ __launch_bounds__(TPB) void ghmc_main(const float* __restrict__ x,
                                                 const int* __restrict__ tgt,
                                                 float* __restrict__ part,   // [2*BINS][nblocks]
                                                 int nvec, int ntotal, int nblocks) {
    __shared__ float lsum[BINS * TPB];  // 10 KB, per-thread private columns
    __shared__ float lcnt[BINS * TPB];  // 10 KB
    const int tid = threadIdx.x;
    #pragma unroll
    for (int b = 0; b < BINS; ++b) {
        lsum[b * TPB + tid] = 0.0f;
        lcnt[b * TPB + tid] = 0.0f;
    }
    // No barrier needed: each thread touches only its own column until reduction.

    const float4* __restrict__ x4 = (const float4*)x;
    const int4*   __restrict__ t4 = (const int4*)tgt;
    const int base = blockIdx.x * (TPB * VEC_ITERS) + tid;

    #pragma unroll
    for (int j = 0; j < VEC_ITERS; ++j) {
        int gi = base + j * TPB;
        if (gi < nvec) {
            float4 xv = x4[gi];
            int4   tv = t4[gi];
            ghmc_accum(xv.x, tv.x, lsum, lcnt, tid);
            ghmc_accum(xv.y, tv.y, lsum, lcnt, tid);
            ghmc_accum(xv.z, tv.z, lsum, lcnt, tid);
            ghmc_accum(xv.w, tv.w, lsum, lcnt, tid);
        }
    }
    // Scalar tail (N not a multiple of 4) — no-op for N = 2^24.
    if (blockIdx.x == 0) {
        for (int i = nvec * 4 + tid; i < ntotal; i += TPB) {
            ghmc_accum(x[i], tgt[i], lsum, lcnt, tid);
        }
    }

    __syncthreads();
    // Tree-reduce the 256 columns for each bin.
    for (int sft = TPB / 2; sft > 0; sft >>= 1) {
        if (tid < sft) {
            #pragma unroll
            for (int b = 0; b < BINS; ++b) {
                lsum[b * TPB + tid] += lsum[b * TPB + tid + sft];
                lcnt[b * TPB + tid] += lcnt[b * TPB + tid + sft];
            }
        }
        __syncthreads();
    }
    // Write partials (no pre-zero, no global atomics): slot per block.
    if (tid < BINS) {
        part[tid * nblocks + blockIdx.x]          = lsum[tid * TPB];
        part[(BINS + tid) * nblocks + blockIdx.x] = lcnt[tid * TPB];
    }
}

// Reduce per-block partials and compute:
//   result = sum_b sum_ce_b / max(cnt_b * nonempty, 1e-6)   (N in beta cancels)
__global__ __launch_bounds__(TPB) void ghmc_final(const float* __restrict__ part,
                                                  float* __restrict__ out, int nblocks) {
    __shared__ float red[2 * BINS * TPB];   // 20 KB
    const int tid = threadIdx.x;
    #pragma unroll
    for (int s = 0; s < 2 * BINS; ++s) {
        float v = 0.0f;
        for (int i = tid; i < nblocks; i += TPB) v += part[s * nblocks + i];
        red[s * TPB + tid] = v;
    }
    __syncthreads();
    for (int sft = TPB / 2; sft > 0; sft >>= 1) {
        if (tid < sft) {
            #pragma unroll
            for (int s = 0; s < 2 * BINS; ++s)
                red[s * TPB + tid] += red[s * TPB + tid + sft];
        }
        __syncthreads();
    }
    if (tid == 0) {
        float ne = 0.0f;
        #pragma unroll
        for (int b = 0; b < BINS; ++b)
            ne += (red[(BINS + b) * TPB] > 0.0f) ? 1.0f : 0.0f;
        float res = 0.0f;
        #pragma unroll
        for (int b = 0; b < BINS; ++b)
            res += red[b * TPB] / fmaxf(red[(BINS + b) * TPB] * ne, 1e-6f);
        out[0] = res;
    }
}

extern "C" void kernel_launch(void* const* d_in, const int* in_sizes, int n_in,
                              void* d_out, int out_size, void* d_ws, size_t ws_size,
                              hipStream_t stream) {
    const float* x   = (const float*)d_in[0];
    const int*   tgt = (const int*)d_in[1];
    float* out  = (float*)d_out;
    float* part = (float*)d_ws;   // needs 2*BINS*nblocks*4 bytes (160 KB at N=2^24)

    int N    = in_sizes[0];
    int nvec = N / 4;
    int nblocks = (nvec + TPB * VEC_ITERS - 1) / (TPB * VEC_ITERS);
    if (nblocks < 1) nblocks = 1;

    ghmc_main<<<nblocks, TPB, 0, stream>>>(x, tgt, part, nvec, N, nblocks);
    ghmc_final<<<1, TPB, 0, stream>>>(part, out, nblocks);
}

// Round 3
// 191.570 us; speedup vs baseline: 1.6857x; 1.6857x over previous
//
#include <hip/hip_runtime.h>

#define BINS 10
#define TPB 256
#define VEC_ITERS 8    // float4 iterations per thread => 32 elements/thread

// Fully register-resident per-element processing. No LDS in the hot loop:
// round 1 (plain LDS RMW) was latency-bound (~240 cyc chain/elem), round 2
// (ds_add_f32 atomics) was throughput-bound (~210 cyc per atomic wave-instr,
// lane-serialized). Registers + predication cost ~50 VALU/elem = ~10.7 us/CU,
// under the memory floor.
__device__ __forceinline__ void ghmc_elem(float z, int t,
                                          float acc[BINS],
                                          unsigned long long& cntpack) {
    float tf = (float)t;
    float az = fabsf(z);
    float e  = __expf(-az);                  // exp(-|z|)
    float q  = 1.0f + e;
    float r  = __builtin_amdgcn_rcpf(q);     // ~1/(1+e)
    float s  = (z >= 0.0f) ? r : e * r;      // sigmoid(z)
    float g  = fabsf(s - tf);                // |sigmoid - t|
    int bin  = (int)(g * 9.9999f);           // g in [0,1]: trunc == floor
    bin = bin < (BINS - 1) ? bin : (BINS - 1);
    // ce = logaddexp(0,z) - z*t = max(z,0) + log(1+exp(-|z|)) - z*t
    float ce = fmaxf(z, 0.0f) - z * tf + __logf(q);
    #pragma unroll
    for (int b = 0; b < BINS; ++b)
        acc[b] += (bin == b) ? ce : 0.0f;    // v_cmp + v_cndmask + v_add
    cntpack += 1ull << (bin * 6);            // 10 x 6-bit packed counters
}

__global__ __launch_bounds__(TPB, 8) void ghmc_main(const float* __restrict__ x,
                                                    const int* __restrict__ tgt,
                                                    float* __restrict__ part,  // [2*BINS][nblocks]
                                                    int nvec, int ntotal, int nblocks) {
    const int tid = threadIdx.x;
    float acc[BINS];
    #pragma unroll
    for (int b = 0; b < BINS; ++b) acc[b] = 0.0f;
    unsigned long long cntpack = 0ull;

    const float4* __restrict__ x4 = (const float4*)x;
    const int4*   __restrict__ t4 = (const int4*)tgt;
    const int base = blockIdx.x * (TPB * VEC_ITERS) + tid;

    #pragma unroll 2
    for (int j = 0; j < VEC_ITERS; ++j) {
        int gi = base + j * TPB;
        if (gi < nvec) {
            float4 xv = x4[gi];
            int4   tv = t4[gi];
            ghmc_elem(xv.x, tv.x, acc, cntpack);
            ghmc_elem(xv.y, tv.y, acc, cntpack);
            ghmc_elem(xv.z, tv.z, acc, cntpack);
            ghmc_elem(xv.w, tv.w, acc, cntpack);
        }
    }
    // Scalar tail (N not a multiple of 4): <=1 extra element/thread, no overflow.
    if (blockIdx.x == 0) {
        for (int i = nvec * 4 + tid; i < ntotal; i += TPB) {
            ghmc_elem(x[i], tgt[i], acc, cntpack);
        }
    }

    // Unpack counts to float (exact: per-lane <= 33, wave sum <= 2112).
    float fcnt[BINS];
    #pragma unroll
    for (int b = 0; b < BINS; ++b)
        fcnt[b] = (float)((unsigned)((cntpack >> (6 * b)) & 63ull));

    // Wave-level shuffle reduction (64 lanes).
    #pragma unroll
    for (int o = 32; o > 0; o >>= 1) {
        #pragma unroll
        for (int b = 0; b < BINS; ++b) {
            acc[b]  += __shfl_down(acc[b], o);
            fcnt[b] += __shfl_down(fcnt[b], o);
        }
    }

    // Cross-wave via tiny LDS (4 waves x 20 floats).
    __shared__ float wred[4][2 * BINS];
    const int wid = tid >> 6, lane = tid & 63;
    if (lane == 0) {
        #pragma unroll
        for (int b = 0; b < BINS; ++b) {
            wred[wid][b]        = acc[b];
            wred[wid][BINS + b] = fcnt[b];
        }
    }
    __syncthreads();
    if (tid < 2 * BINS) {
        float v = wred[0][tid] + wred[1][tid] + wred[2][tid] + wred[3][tid];
        part[tid * nblocks + blockIdx.x] = v;   // every slot written: no pre-zero
    }
}

// result = sum_b sum_ce_b / max(cnt_b * nonempty, 1e-6)   (N in beta cancels)
__global__ __launch_bounds__(TPB) void ghmc_final(const float* __restrict__ part,
                                                  float* __restrict__ out, int nblocks) {
    __shared__ float red[2 * BINS * TPB];
    const int tid = threadIdx.x;
    #pragma unroll
    for (int s = 0; s < 2 * BINS; ++s) {
        float v = 0.0f;
        for (int i = tid; i < nblocks; i += TPB) v += part[s * nblocks + i];
        red[s * TPB + tid] = v;
    }
    __syncthreads();
    for (int sft = TPB / 2; sft > 0; sft >>= 1) {
        if (tid < sft) {
            #pragma unroll
            for (int s = 0; s < 2 * BINS; ++s)
                red[s * TPB + tid] += red[s * TPB + tid + sft];
        }
        __syncthreads();
    }
    if (tid == 0) {
        float ne = 0.0f;
        #pragma unroll
        for (int b = 0; b < BINS; ++b)
            ne += (red[(BINS + b) * TPB] > 0.0f) ? 1.0f : 0.0f;
        float res = 0.0f;
        #pragma unroll
        for (int b = 0; b < BINS; ++b)
            res += red[b * TPB] / fmaxf(red[(BINS + b) * TPB] * ne, 1e-6f);
        out[0] = res;
    }
}

extern "C" void kernel_launch(void* const* d_in, const int* in_sizes, int n_in,
                              void* d_out, int out_size, void* d_ws, size_t ws_size,
                              hipStream_t stream) {
    const float* x   = (const float*)d_in[0];
    const int*   tgt = (const int*)d_in[1];
    float* out  = (float*)d_out;
    float* part = (float*)d_ws;   // 2*BINS*nblocks*4 B (160 KB at N=2^24)

    int N    = in_sizes[0];
    int nvec = N / 4;
    int nblocks = (nvec + TPB * VEC_ITERS - 1) / (TPB * VEC_ITERS);
    if (nblocks < 1) nblocks = 1;

    ghmc_main<<<nblocks, TPB, 0, stream>>>(x, tgt, part, nvec, N, nblocks);
    ghmc_final<<<1, TPB, 0, stream>>>(part, out, nblocks);
}